// Round 3
// baseline (546.284 us; speedup 1.0000x reference)
//
#include <hip/hip_runtime.h>
#include <hip/hip_bf16.h>

// DenseRecurrentConsciousnessNet on MI355X (gfx950)
// B=65536, H=512, S=256, D=64.
// R3: (a) algebraic: c_mean = mean(content) @ W_content + b  ->  content GEMM
//     replaced by a BW-bound column-mean kernel; main GEMM is query-only N=512.
//     (b) m97-style 2-barrier K-loop, wt via global_load_lds(16B), LDS 34.8KB
//     -> 4 blocks/CU (16 waves). (c) slim epilogue: shuffle-based softmax
//     stats, only read-P round-trips LDS for the PV transpose.

typedef short short8 __attribute__((ext_vector_type(8)));
typedef float floatx4 __attribute__((ext_vector_type(4)));

// ws byte offsets
#define WS_WT    0          // bf16 [512][512] = 524288 B   (rows = N cols, [n][k])
#define WS_MEMT  524288     // bf16 [64][256]  = 32768 B
#define WS_BFULL 557056     // f32  [512]      = 2048 B
#define WS_WSUM  559104     // f32  [256]      = 1024 B
#define WS_CMH   560128     // f32  [512]      = 2048 B  (column sums of content)

__device__ __forceinline__ unsigned short f2b(float f) {
  unsigned u = __float_as_uint(f);
  u += 0x7fffu + ((u >> 16) & 1u);          // round-to-nearest-even
  return (unsigned short)(u >> 16);
}
__device__ __forceinline__ unsigned cvt2(float x, float y) {
  union { __hip_bfloat162 h; unsigned u; } c;
  c.h = __float22bfloat162_rn(make_float2(x, y));
  return c.u;
}
__device__ __forceinline__ void async16(const void* g, void* l) {
  __builtin_amdgcn_global_load_lds(
      (const __attribute__((address_space(1))) unsigned int*)g,
      (__attribute__((address_space(3))) unsigned int*)l, 16, 0, 0);
}

// ---------------- init: pack weights / memory^T / biases, zero accumulators --
__global__ void drcn_init(const float* __restrict__ W_read, const float* __restrict__ W_write,
                          const float* __restrict__ b_read, const float* __restrict__ b_write,
                          const float* __restrict__ memory,
                          unsigned short* __restrict__ Wt, unsigned short* __restrict__ memT,
                          float* __restrict__ bfull, float* __restrict__ w_sum,
                          float* __restrict__ cmH) {
  int idx = blockIdx.x * 256 + threadIdx.x;
  if (idx < 262144) {                       // Wt[n][k] = W[k][n], bf16
    int n = idx >> 9, k = idx & 511;
    float v = (n < 256) ? W_read[k * 256 + n] : W_write[k * 256 + (n - 256)];
    Wt[idx] = f2b(v);
  } else if (idx < 278528) {                // memT[d][s] = memory[s][d]
    int i = idx - 262144;
    int d = i >> 8, s = i & 255;
    memT[i] = f2b(memory[s * 64 + d]);
  } else if (idx < 279040) {                // bias [512] = b_read|b_write
    int n = idx - 278528;
    bfull[n] = (n < 256) ? b_read[n] : b_write[n - 256];
  } else if (idx < 279296) {
    w_sum[idx - 279040] = 0.0f;
  } else if (idx < 279808) {
    cmH[idx - 279296] = 0.0f;
  }
}

// ---------------- content column sums (for c_mean) — pure BW ----------------
__global__ __launch_bounds__(256) void drcn_cmean(const float* __restrict__ content,
                                                  float* __restrict__ cmH) {
  __shared__ float4 red[256];
  const int t = threadIdx.x;
  const int chunk = t & 127, rg = t >> 7;   // float4 column chunk, row group
  const float4* src = (const float4*)content +
      (size_t)(blockIdx.x * 32 + rg * 16) * 128 + chunk;
  float4 s = {0.f, 0.f, 0.f, 0.f};
  #pragma unroll
  for (int i = 0; i < 16; i++) {
    float4 v = src[(size_t)i * 128];
    s.x += v.x; s.y += v.y; s.z += v.z; s.w += v.w;
  }
  red[t] = s;
  __syncthreads();
  if (t < 128) {
    float4 a = red[t], b = red[t + 128];
    atomicAdd(&cmH[t * 4 + 0], a.x + b.x);
    atomicAdd(&cmH[t * 4 + 1], a.y + b.y);
    atomicAdd(&cmH[t * 4 + 2], a.z + b.z);
    atomicAdd(&cmH[t * 4 + 3], a.w + b.w);
  }
}

// ---------------- main: [32,512]@[512,512] + dual softmax + P@memory --------
__global__ __launch_bounds__(256, 4) void drcn_main(
    const float* __restrict__ query, const unsigned short* __restrict__ Wt,
    const float* __restrict__ bfull, const unsigned short* __restrict__ memT,
    float* __restrict__ w_sum, float* __restrict__ out) {
  // staging: wt [512][32] bf16 @0 (32768), qa [32][32] bf16 @32768 (2048)
  // epilogue union: pbuf bf16 [32][264] @0 (16896), pmx f32[128] @32768,
  //                 psum f32[128] @33280
  __shared__ __align__(16) char smem[34816];
  unsigned short* wt = (unsigned short*)smem;
  unsigned short* qa = (unsigned short*)(smem + 32768);
  unsigned short* pbuf = (unsigned short*)smem;
  float* pmx  = (float*)(smem + 32768);
  float* psum = (float*)(smem + 33280);

  const int t = threadIdx.x;
  const int wv = t >> 6, ln = t & 63, ln15 = ln & 15, quad = ln >> 4;
  const int m0 = blockIdx.x * 32;

  float bias[8];
  #pragma unroll
  for (int j = 0; j < 8; j++) bias[j] = bfull[wv * 128 + j * 16 + ln15];

  floatx4 acc[2][8];
  #pragma unroll
  for (int mt = 0; mt < 2; mt++)
    #pragma unroll
    for (int j = 0; j < 8; j++) {
      floatx4 z = {0.f, 0.f, 0.f, 0.f};
      acc[mt][j] = z;
    }

  // wave wv stages its OWN 128 B-rows: chunks c = wv*8+i (16 rows each)
  const unsigned short* wsrc = Wt + (size_t)(wv * 128 + (ln >> 2)) * 512 + (ln & 3) * 8;
  char* wdst = smem + (wv * 8) * 1024 + ln * 16;
  const int arow = t >> 3, acol = (t & 7) * 4;
  const float* qsrc = query + (size_t)(m0 + arow) * 512 + acol;

  for (int it = 0; it < 16; ++it) {
    __syncthreads();
    #pragma unroll
    for (int i = 0; i < 8; i++)
      async16(wsrc + (size_t)i * 16 * 512 + it * 32, wdst + i * 1024);
    {
      float4 f = *(const float4*)(qsrc + it * 32);
      *(uint2*)(qa + arow * 32 + acol) = make_uint2(cvt2(f.x, f.y), cvt2(f.z, f.w));
    }
    __syncthreads();   // compiler emits vmcnt(0) lgkmcnt(0) drain here

    short8 aq0 = *(const short8*)(qa + ln15 * 32 + quad * 8);
    short8 aq1 = *(const short8*)(qa + (16 + ln15) * 32 + quad * 8);
    #pragma unroll
    for (int j = 0; j < 8; j++) {
      short8 b = *(const short8*)(wt + (wv * 128 + j * 16 + ln15) * 32 + quad * 8);
      acc[0][j] = __builtin_amdgcn_mfma_f32_16x16x32_bf16(aq0, b, acc[0][j], 0, 0, 0);
      acc[1][j] = __builtin_amdgcn_mfma_f32_16x16x32_bf16(aq1, b, acc[1][j], 0, 0, 0);
    }
  }

  // ---- epilogue: bias + dual softmax stats via shuffles + tiny LDS ----
  #pragma unroll
  for (int mt = 0; mt < 2; mt++)
    #pragma unroll
    for (int j = 0; j < 8; j++)
      #pragma unroll
      for (int r = 0; r < 4; r++) acc[mt][j][r] += bias[j];

  float rmx[2][4];
  #pragma unroll
  for (int mt = 0; mt < 2; mt++)
    #pragma unroll
    for (int r = 0; r < 4; r++) {
      float m = -3.0e38f;
      #pragma unroll
      for (int j = 0; j < 8; j++) m = fmaxf(m, acc[mt][j][r]);
      rmx[mt][r] = m;
    }
  #pragma unroll
  for (int b = 1; b <= 8; b <<= 1)
    #pragma unroll
    for (int mt = 0; mt < 2; mt++)
      #pragma unroll
      for (int r = 0; r < 4; r++) rmx[mt][r] = fmaxf(rmx[mt][r], __shfl_xor(rmx[mt][r], b));
  if (ln15 == 0) {
    #pragma unroll
    for (int mt = 0; mt < 2; mt++)
      #pragma unroll
      for (int r = 0; r < 4; r++) pmx[wv * 32 + mt * 16 + quad * 4 + r] = rmx[mt][r];
  }
  __syncthreads();

  float cmx[2][4], rsm[2][4];
  #pragma unroll
  for (int mt = 0; mt < 2; mt++)
    #pragma unroll
    for (int r = 0; r < 4; r++) {
      int row = mt * 16 + quad * 4 + r;
      cmx[mt][r] = fmaxf(pmx[wv * 32 + row], pmx[(wv ^ 1) * 32 + row]);
      rsm[mt][r] = 0.f;
    }
  #pragma unroll
  for (int mt = 0; mt < 2; mt++)
    #pragma unroll
    for (int j = 0; j < 8; j++)
      #pragma unroll
      for (int r = 0; r < 4; r++) {
        float e = __expf(acc[mt][j][r] - cmx[mt][r]);
        acc[mt][j][r] = e;
        rsm[mt][r] += e;
      }
  #pragma unroll
  for (int b = 1; b <= 8; b <<= 1)
    #pragma unroll
    for (int mt = 0; mt < 2; mt++)
      #pragma unroll
      for (int r = 0; r < 4; r++) rsm[mt][r] += __shfl_xor(rsm[mt][r], b);
  if (ln15 == 0) {
    #pragma unroll
    for (int mt = 0; mt < 2; mt++)
      #pragma unroll
      for (int r = 0; r < 4; r++) psum[wv * 32 + mt * 16 + quad * 4 + r] = rsm[mt][r];
  }
  __syncthreads();

  float inv_[2][4];
  #pragma unroll
  for (int mt = 0; mt < 2; mt++)
    #pragma unroll
    for (int r = 0; r < 4; r++) {
      int row = mt * 16 + quad * 4 + r;
      inv_[mt][r] = 1.0f / (psum[wv * 32 + row] + psum[(wv ^ 1) * 32 + row]);
    }

  if (wv < 2) {
    // read-P -> LDS transpose buffer (bf16, pitch 264 elems)
    #pragma unroll
    for (int mt = 0; mt < 2; mt++)
      #pragma unroll
      for (int j = 0; j < 8; j++)
        #pragma unroll
        for (int r = 0; r < 4; r++) {
          int row = mt * 16 + quad * 4 + r;
          pbuf[row * 264 + wv * 128 + j * 16 + ln15] = f2b(acc[mt][j][r] * inv_[mt][r]);
        }
  } else {
    // write-softmax column sums straight to global
    #pragma unroll
    for (int j = 0; j < 8; j++) {
      float s = 0.f;
      #pragma unroll
      for (int mt = 0; mt < 2; mt++)
        #pragma unroll
        for (int r = 0; r < 4; r++) s += acc[mt][j][r] * inv_[mt][r];
      s += __shfl_xor(s, 16);
      s += __shfl_xor(s, 32);
      if (quad == 0) atomicAdd(&w_sum[(wv - 2) * 128 + j * 16 + ln15], s);
    }
  }
  __syncthreads();

  // ---- PV: read_content = P @ memory (B-frags from L2-resident memT) ----
  {
    const int mt = wv & 1, dn0 = (wv >> 1) * 2;
    floatx4 ra[2];
    floatx4 z = {0.f, 0.f, 0.f, 0.f};
    ra[0] = z; ra[1] = z;
    #pragma unroll
    for (int ks = 0; ks < 8; ks++) {
      int s0 = ks * 32 + quad * 8;
      short8 a = *(const short8*)(pbuf + (mt * 16 + ln15) * 264 + s0);
      #pragma unroll
      for (int dt = 0; dt < 2; dt++) {
        short8 bb = *(const short8*)(memT + ((dn0 + dt) * 16 + ln15) * 256 + s0);
        ra[dt] = __builtin_amdgcn_mfma_f32_16x16x32_bf16(a, bb, ra[dt], 0, 0, 0);
      }
    }
    #pragma unroll
    for (int dt = 0; dt < 2; dt++)
      #pragma unroll
      for (int rr = 0; rr < 4; rr++) {
        int orow = m0 + mt * 16 + quad * 4 + rr;
        out[(size_t)orow * 64 + (dn0 + dt) * 16 + ln15] = ra[dt][rr];
      }
  }
}

// ---------------- final: pc = cmean@W_content + b; EMA + age ----------------
__global__ __launch_bounds__(256) void drcn_final(
    const float* __restrict__ memory, const float* __restrict__ age,
    const float* __restrict__ w_sum, const float* __restrict__ cmH,
    const float* __restrict__ W_content, const float* __restrict__ b_content,
    float* __restrict__ out_mem, float* __restrict__ out_age) {
  __shared__ float part[4][64];
  __shared__ float pc[64];
  const int t = threadIdx.x;
  {
    int d = t & 63, p = t >> 6;
    float s = 0.f;
    for (int h = p * 128; h < p * 128 + 128; h++) s += cmH[h] * W_content[h * 64 + d];
    part[p][d] = s;
  }
  __syncthreads();
  if (t < 64)
    pc[t] = b_content[t] +
            (part[0][t] + part[1][t] + part[2][t] + part[3][t]) * (1.0f / 65536.0f);
  __syncthreads();
  int idx = blockIdx.x * 256 + t;           // 16384 = 256 slots * 64
  int s_ = idx >> 6, d = idx & 63;
  float wm = w_sum[s_] * (1.0f / 65536.0f);
  bool act = wm > 0.01f;
  float cons = 1.0f / (1.0f + __expf(-age[s_] * 0.1f));
  float alpha = act ? wm * cons : 0.0f;
  out_mem[idx] = (1.0f - alpha) * memory[idx] + alpha * pc[d];
  if (d == 0) out_age[s_] = age[s_] + (act ? 1.0f : 0.0f);
}

extern "C" void kernel_launch(void* const* d_in, const int* in_sizes, int n_in,
                              void* d_out, int out_size, void* d_ws, size_t ws_size,
                              hipStream_t stream) {
  (void)in_sizes; (void)n_in; (void)out_size; (void)ws_size;
  const float* query     = (const float*)d_in[0];
  const float* content   = (const float*)d_in[1];
  const float* memory    = (const float*)d_in[2];
  const float* mem_age   = (const float*)d_in[3];
  const float* W_read    = (const float*)d_in[4];
  const float* b_read    = (const float*)d_in[5];
  const float* W_write   = (const float*)d_in[6];
  const float* b_write   = (const float*)d_in[7];
  const float* W_content = (const float*)d_in[8];
  const float* b_content = (const float*)d_in[9];
  float* out = (float*)d_out;
  char* ws = (char*)d_ws;
  unsigned short* Wt   = (unsigned short*)(ws + WS_WT);
  unsigned short* memT = (unsigned short*)(ws + WS_MEMT);
  float* bfull = (float*)(ws + WS_BFULL);
  float* w_sum = (float*)(ws + WS_WSUM);
  float* cmH   = (float*)(ws + WS_CMH);

  drcn_init<<<1093, 256, 0, stream>>>(W_read, W_write, b_read, b_write, memory,
                                      Wt, memT, bfull, w_sum, cmH);
  drcn_cmean<<<2048, 256, 0, stream>>>(content, cmH);
  drcn_main<<<2048, 256, 0, stream>>>(query, Wt, bfull, memT, w_sum, out);
  drcn_final<<<64, 256, 0, stream>>>(memory, mem_age, w_sum, cmH, W_content,
                                     b_content, out + 4194304, out + 4210688);
}